// Round 3
// baseline (246.515 us; speedup 1.0000x reference)
//
#include <hip/hip_runtime.h>

#define NF 36
#define QN 100
#define TN 20
#define CN 92
#define NB 64
#define LSTRIDE 93   // odd mod 32 -> row-strided LDS reads are 2-way (free)

// ---------------- Kernel A: cost matrices (memory-optimal) ----------------
__global__ __launch_bounds__(128) void cost_kernel(
    const float* __restrict__ logits,   // [64][3600][92]
    const float* __restrict__ pboxes,   // [64][3600][4]
    const int*   __restrict__ tlabels,  // [36][64][20]
    const float* __restrict__ tboxes,   // [36][64][20][4]
    float* __restrict__ out_cost)       // [64][36][100][20]
{
    const int bf = blockIdx.x;          // b*36 + f
    const int b  = bf / NF;
    const int f  = bf % NF;
    const int tid = threadIdx.x;

    __shared__ float Llds[QN * LSTRIDE];   // 37.2 KB staged logits
    __shared__ float ben[TN][101];         // cost^T staging for coalesced write
    __shared__ int   slab[TN];
    __shared__ float tbr[TN][4];           // raw cxcywh
    __shared__ float tbx[TN][4];           // xyxy
    __shared__ float tarea[TN];

    // stage targets
    if (tid < TN) {
        const int base = (f * NB + b) * TN + tid;
        slab[tid] = tlabels[base];
        const float* tb = tboxes + (size_t)base * 4;
        float cx = tb[0], cy = tb[1], w = tb[2], h = tb[3];
        tbr[tid][0] = cx; tbr[tid][1] = cy; tbr[tid][2] = w; tbr[tid][3] = h;
        float x1 = cx - 0.5f * w, y1 = cy - 0.5f * h;
        float x2 = cx + 0.5f * w, y2 = cy + 0.5f * h;
        tbx[tid][0] = x1; tbx[tid][1] = y1; tbx[tid][2] = x2; tbx[tid][3] = y2;
        tarea[tid] = (x2 - x1) * (y2 - y1);
    }

    // stage logits: 100 rows x 92 = 2300 float4, fully coalesced, read ONCE from HBM
    {
        const float4* G4 = reinterpret_cast<const float4*>(
            logits + ((size_t)b * (NF * QN) + (size_t)f * QN) * CN);
        for (int i = tid; i < (QN * CN) / 4; i += 128) {
            float4 v = G4[i];
            int row = i / 23;              // 92/4 = 23 float4 per row (no row spanning)
            int col = (i - row * 23) * 4;
            float* dst = &Llds[row * LSTRIDE + col];
            dst[0] = v.x; dst[1] = v.y; dst[2] = v.z; dst[3] = v.w;
        }
    }
    __syncthreads();

    if (tid < QN) {
        const float* L = &Llds[tid * LSTRIDE];
        // two-pass softmax, same sequential order as the passing kernel -> identical bits
        float m = -INFINITY;
        for (int c = 0; c < CN; ++c) m = fmaxf(m, L[c]);
        float s = 0.f;
        for (int c = 0; c < CN; ++c) s += expf(L[c] - m);

        const size_t row = (size_t)b * (NF * QN) + (size_t)f * QN + tid;
        float4 pbv = reinterpret_cast<const float4*>(pboxes)[row];   // coalesced
        float cx = pbv.x, cy = pbv.y, w = pbv.z, h = pbv.w;
        float px1 = cx - 0.5f * w, py1 = cy - 0.5f * h;
        float px2 = cx + 0.5f * w, py2 = cy + 0.5f * h;
        float a1 = (px2 - px1) * (py2 - py1);

        for (int t = 0; t < TN; ++t) {
            float p = expf(L[slab[t]] - m) / s;
            float cb = fabsf(cx - tbr[t][0]) + fabsf(cy - tbr[t][1]);
            cb = cb + fabsf(w - tbr[t][2]);
            cb = cb + fabsf(h - tbr[t][3]);
            float ltx = fmaxf(px1, tbx[t][0]), lty = fmaxf(py1, tbx[t][1]);
            float rbx = fminf(px2, tbx[t][2]), rby = fminf(py2, tbx[t][3]);
            float wx = fmaxf(rbx - ltx, 0.f), wy = fmaxf(rby - lty, 0.f);
            float inter = wx * wy;
            float uni = a1 + tarea[t] - inter;
            float iou = inter / uni;
            float ex1 = fminf(px1, tbx[t][0]), ey1 = fminf(py1, tbx[t][1]);
            float ex2 = fmaxf(px2, tbx[t][2]), ey2 = fmaxf(py2, tbx[t][3]);
            float ew = fmaxf(ex2 - ex1, 0.f), eh = fmaxf(ey2 - ey1, 0.f);
            float ae = ew * eh;
            float giou = iou - (ae - uni) / ae;
            float cost = (-p) + 5.0f * cb - 2.0f * giou;
            ben[t][tid] = -cost;
        }
    }
    __syncthreads();

    // coalesced cost write-out
    {
        float4* dst = reinterpret_cast<float4*>(out_cost + (size_t)bf * (QN * TN));
        for (int i = tid; i < (QN * TN) / 4; i += 128) {
            int k = i * 4;
            float4 v;
            v.x = -ben[(k + 0) % TN][(k + 0) / TN];
            v.y = -ben[(k + 1) % TN][(k + 1) / TN];
            v.z = -ben[(k + 2) % TN][(k + 2) / TN];
            v.w = -ben[(k + 3) % TN][(k + 3) / TN];
            dst[i] = v;
        }
    }
}

// ---------------- Kernel B: one-wave auction per problem ----------------
__global__ __launch_bounds__(64) void auction_kernel(
    const float* __restrict__ cost_in,  // [2304][100][20]
    float* __restrict__ out_pred,       // [64][36][20]
    float* __restrict__ out_tgt)        // [64][36][20]
{
    const int bf = blockIdx.x;
    const int lane = threadIdx.x;

    __shared__ float ben[TN][101];      // benefit[t][q]
    __shared__ float price[QN];
    __shared__ int   owner[QN];
    __shared__ int   obj_of[TN];
    __shared__ float pv0[64], pv1[64];
    __shared__ int   pi0[64];
    __shared__ float bidv[TN];
    __shared__ int   bo[TN];

    // load cost tile (coalesced, mostly L2-warm right after kernel A), transpose, min/max
    float mn = INFINITY, mx = -INFINITY;
    {
        const float4* C4 = reinterpret_cast<const float4*>(cost_in + (size_t)bf * (QN * TN));
        #pragma unroll
        for (int k = 0; k < 8; ++k) {
            int i = lane + 64 * k;
            if (i < (QN * TN) / 4) {
                float4 v = C4[i];
                int q  = i / 5;             // 20/4 = 5 float4 per q-row
                int t0 = (i - q * 5) * 4;
                ben[t0 + 0][q] = -v.x; ben[t0 + 1][q] = -v.y;
                ben[t0 + 2][q] = -v.z; ben[t0 + 3][q] = -v.w;
                mn = fminf(mn, fminf(fminf(v.x, v.y), fminf(v.z, v.w)));
                mx = fmaxf(mx, fmaxf(fmaxf(v.x, v.y), fmaxf(v.z, v.w)));
            }
        }
    }
    #pragma unroll
    for (int off = 32; off > 0; off >>= 1) {
        mn = fminf(mn, __shfl_xor(mn, off, 64));
        mx = fmaxf(mx, __shfl_xor(mx, off, 64));
    }
    // spread = max(benefit)-min(benefit)+1e-6 = (-mn)-(-mx)+1e-6 (float-identical to ref)
    const float eps = (((-mn) - (-mx)) + 1e-6f) / 1000.0f;

    if (lane < QN) { price[lane] = 0.f; owner[lane] = -1; }
    if (lane + 64 < QN) { price[lane + 64] = 0.f; owner[lane + 64] = -1; }
    if (lane < TN) obj_of[lane] = -1;

    // auction: Jacobi, exact reference dynamics, single-wave (barriers ~free)
    for (int it = 0; it < 20000; ++it) {
        __syncthreads();
        unsigned long long un = __ballot((lane < TN) ? (obj_of[lane] < 0) : false);
        if (un == 0ull) break;

        // partial top-2: lane = t*3 + j, chunks [0,34) [34,68) [68,100)
        if (lane < 60) {
            int t = lane / 3, j = lane - t * 3;
            if (obj_of[t] < 0) {
                const float* rowp = ben[t];
                int q0 = j * 34;
                float v0 = -INFINITY, v1 = -INFINITY; int i0 = q0;
                #pragma unroll
                for (int k = 0; k < 34; ++k) {
                    int q = q0 + k;
                    if (q < QN) {
                        float v = rowp[q] - price[q];
                        if (v > v0) { v1 = v0; v0 = v; i0 = q; }
                        else if (v > v1) { v1 = v; }
                    }
                }
                pv0[lane] = v0; pv1[lane] = v1; pi0[lane] = i0;
            }
        }
        __syncthreads();

        // ordered 3-way merge per bidder (value- and tie-break-exact vs serial scan)
        float mybid = -INFINITY; int myq = -1;
        if (lane < TN) {
            if (obj_of[lane] < 0) {
                int base = lane * 3;
                float v0 = pv0[base], v1 = pv1[base]; int i0 = pi0[base];
                #pragma unroll
                for (int j = 1; j < 3; ++j) {
                    float bv0 = pv0[base + j], bv1 = pv1[base + j]; int bi0 = pi0[base + j];
                    if (bv0 > v0) { v1 = fmaxf(v0, bv1); v0 = bv0; i0 = bi0; }
                    else          { v1 = fmaxf(bv0, v1); }
                }
                mybid = price[i0] + (v0 - v1) + eps;   // exact ref op order
                myq = i0;
            }
            bidv[lane] = mybid; bo[lane] = myq;
        }
        __syncthreads();

        // per-bidder win check: lane t wins q iff no t2 on same q with (bid> or (bid== && t2<t))
        if (lane < TN && mybid != -INFINITY) {
            bool lose = false;
            #pragma unroll
            for (int t2 = 0; t2 < TN; ++t2) {
                float bv = bidv[t2]; int ob = bo[t2];     // broadcast LDS reads
                lose = lose || (ob == myq && (bv > mybid || (bv == mybid && t2 < lane)));
            }
            if (!lose) {
                int q = myq;
                int old = owner[q];                        // winners have distinct q
                if (old >= 0) obj_of[old] = -1;            // evictees disjoint from winners
                obj_of[lane] = q;
                owner[q] = lane;
                price[q] = mybid;                          // winner's bid == best_bid[q]
            }
        }
    }
    __syncthreads();

    // stable argsort of obj_of (rank computation)
    if (lane < TN) {
        int v = obj_of[lane];
        int r = 0;
        for (int u = 0; u < TN; ++u) {
            int w = obj_of[u];
            r += (w < v) || (w == v && u < lane);
        }
        out_pred[(size_t)bf * TN + r] = (float)v;
        out_tgt[(size_t)bf * TN + r]  = (float)lane;
    }
}

extern "C" void kernel_launch(void* const* d_in, const int* in_sizes, int n_in,
                              void* d_out, int out_size, void* d_ws, size_t ws_size,
                              hipStream_t stream) {
    const float* logits  = (const float*)d_in[0];
    const float* pboxes  = (const float*)d_in[1];
    const int*   tlabels = (const int*)d_in[2];
    const float* tboxes  = (const float*)d_in[3];

    float* out = (float*)d_out;
    float* out_cost = out;                                   // 64*36*100*20
    float* out_pred = out + (size_t)NB * NF * QN * TN;       // 64*36*20
    float* out_tgt  = out_pred + (size_t)NB * NF * TN;       // 64*36*20

    hipLaunchKernelGGL(cost_kernel, dim3(NB * NF), dim3(128), 0, stream,
                       logits, pboxes, tlabels, tboxes, out_cost);
    hipLaunchKernelGGL(auction_kernel, dim3(NB * NF), dim3(64), 0, stream,
                       out_cost, out_pred, out_tgt);
}

// Round 4
// 180.557 us; speedup vs baseline: 1.3653x; 1.3653x over previous
//
#include <hip/hip_runtime.h>

#define NF 36
#define QN 100
#define TN 20
#define CN 92
#define NB 64
#define BSTR 104   // ben/price row pad; [100..103] are -INF / 0 sentinels

__global__ __launch_bounds__(64) void matcher_kernel(
    const float* __restrict__ logits,   // [64][3600][92]
    const float* __restrict__ pboxes,   // [64][3600][4]
    const int*   __restrict__ tlabels,  // [36][64][20]
    const float* __restrict__ tboxes,   // [36][64][20][4]
    float* __restrict__ out_cost,       // [64][36][100][20]
    float* __restrict__ out_pred,       // [64][36][20]
    float* __restrict__ out_tgt)        // [64][36][20]
{
    const int bf = blockIdx.x;          // b*36 + f
    const int b  = bf / NF;
    const int f  = bf % NF;
    const int lane = threadIdx.x;

    __shared__ float ben[TN][BSTR];     // benefit[t][q] = -cost[q][t]
    __shared__ float price[BSTR];
    __shared__ int   owner[QN];
    __shared__ float bidv[TN];
    __shared__ int   bo[TN];
    __shared__ int   evict[TN];
    __shared__ int   objl[TN];
    __shared__ int   slab[TN];
    __shared__ float tbr[TN][4];        // raw cxcywh
    __shared__ float tbx[TN][4];        // xyxy
    __shared__ float tarea[TN];

    // ---- stage targets ----
    if (lane < TN) {
        const int base = (f * NB + b) * TN + lane;
        slab[lane] = tlabels[base];
        const float* tb = tboxes + (size_t)base * 4;
        float cx = tb[0], cy = tb[1], w = tb[2], h = tb[3];
        tbr[lane][0] = cx; tbr[lane][1] = cy; tbr[lane][2] = w; tbr[lane][3] = h;
        float x1 = cx - 0.5f * w, y1 = cy - 0.5f * h;
        float x2 = cx + 0.5f * w, y2 = cy + 0.5f * h;
        tbx[lane][0] = x1; tbx[lane][1] = y1; tbx[lane][2] = x2; tbx[lane][3] = y2;
        tarea[lane] = (x2 - x1) * (y2 - y1);
        evict[lane] = 0;
    }
    __syncthreads();

    // ---- cost phase: register-resident logits, 2 passes over q ----
    float mn = INFINITY, mx = -INFINITY;
    for (int p = 0; p < 2; ++p) {
        const int q = lane + 64 * p;
        if (q < QN) {
            const size_t row = (size_t)b * (NF * QN) + (size_t)f * QN + q;
            const float* L = logits + row * CN;
            const float4* L4 = reinterpret_cast<const float4*>(L);
            float4 r[23];
            #pragma unroll
            for (int i = 0; i < 23; ++i) r[i] = L4[i];
            // sequential c-order max then exp-sum (bit-identical to passing kernels)
            float m = -INFINITY;
            #pragma unroll
            for (int i = 0; i < 23; ++i) {
                float4 v = r[i];
                m = fmaxf(m, v.x); m = fmaxf(m, v.y); m = fmaxf(m, v.z); m = fmaxf(m, v.w);
            }
            float s = 0.f;
            #pragma unroll
            for (int i = 0; i < 23; ++i) {
                float4 v = r[i];
                s += expf(v.x - m); s += expf(v.y - m); s += expf(v.z - m); s += expf(v.w - m);
            }

            float4 pbv = reinterpret_cast<const float4*>(pboxes)[row];
            float cx = pbv.x, cy = pbv.y, w = pbv.z, h = pbv.w;
            float px1 = cx - 0.5f * w, py1 = cy - 0.5f * h;
            float px2 = cx + 0.5f * w, py2 = cy + 0.5f * h;
            float a1 = (px2 - px1) * (py2 - py1);

            for (int t = 0; t < TN; ++t) {
                float pc = expf(L[slab[t]] - m) / s;   // L1-warm gather
                float cb = fabsf(cx - tbr[t][0]) + fabsf(cy - tbr[t][1]);
                cb = cb + fabsf(w - tbr[t][2]);
                cb = cb + fabsf(h - tbr[t][3]);
                float ltx = fmaxf(px1, tbx[t][0]), lty = fmaxf(py1, tbx[t][1]);
                float rbx = fminf(px2, tbx[t][2]), rby = fminf(py2, tbx[t][3]);
                float wx = fmaxf(rbx - ltx, 0.f), wy = fmaxf(rby - lty, 0.f);
                float inter = wx * wy;
                float uni = a1 + tarea[t] - inter;
                float iou = inter / uni;
                float ex1 = fminf(px1, tbx[t][0]), ey1 = fminf(py1, tbx[t][1]);
                float ex2 = fmaxf(px2, tbx[t][2]), ey2 = fmaxf(py2, tbx[t][3]);
                float ew = fmaxf(ex2 - ex1, 0.f), eh = fmaxf(ey2 - ey1, 0.f);
                float ae = ew * eh;
                float giou = iou - (ae - uni) / ae;
                float cost = (-pc) + 5.0f * cb - 2.0f * giou;
                ben[t][q] = -cost;
                mn = fminf(mn, cost);
                mx = fmaxf(mx, cost);
            }
        }
    }

    // init price/owner + sentinels (before the barrier)
    for (int i = lane; i < BSTR; i += 64) price[i] = 0.f;
    for (int i = lane; i < QN; i += 64) owner[i] = -1;
    if (lane < TN) {
        ben[lane][100] = -INFINITY; ben[lane][101] = -INFINITY;
        ben[lane][102] = -INFINITY; ben[lane][103] = -INFINITY;
    }
    __syncthreads();

    // eps (exact: spread = (-mn)-(-mx)+1e-6, /1000) — min/max exact under any order
    #pragma unroll
    for (int off = 32; off > 0; off >>= 1) {
        mn = fminf(mn, __shfl_xor(mn, off, 64));
        mx = fmaxf(mx, __shfl_xor(mx, off, 64));
    }
    const float eps = (((-mn) - (-mx)) + 1e-6f) / 1000.0f;

    // coalesced cost write-out from LDS
    {
        float4* dst = reinterpret_cast<float4*>(out_cost + (size_t)bf * (QN * TN));
        for (int i = lane; i < (QN * TN) / 4; i += 64) {
            int k = i * 4;
            int q = k / TN, t0 = k - q * TN;   // 20%4==0: never spans q
            float4 v;
            v.x = -ben[t0 + 0][q]; v.y = -ben[t0 + 1][q];
            v.z = -ben[t0 + 2][q]; v.w = -ben[t0 + 3][q];
            dst[i] = v;
        }
    }

    // ---- benefit chunk -> registers: lane = t*3 + j, chunks q0 = 0/34/68, 34 wide ----
    const int myt = lane / 3;                       // 20,21 for lanes 60..63 (spectators)
    const int jj  = lane - myt * 3;
    const int q0  = jj * 34;                        // <= 68; scan reads up to 101 < BSTR
    const bool is_leader = (lane < 60) && (jj == 0);
    float breg[34];
    {
        const int tt = (lane < 60) ? myt : 0;
        #pragma unroll
        for (int k = 0; k < 34; ++k) breg[k] = ben[tt][q0 + k];
    }
    int myobj = -1;

    // ---- auction: Jacobi, exact reference dynamics, single-wave ----
    for (int it = 0; it < 20000; ++it) {
        unsigned long long U = __ballot(is_leader && (myobj < 0));  // bits at 3t
        if (U == 0ull) break;

        // branchless top-2 over my chunk (strict > keeps lowest q on ties)
        float v0 = -INFINITY, v1 = -INFINITY; int i0 = q0;
        #pragma unroll
        for (int k = 0; k < 34; ++k) {
            float v = breg[k] - price[q0 + k];
            bool c = v > v0;
            v1 = c ? v0 : fmaxf(v1, v);
            i0 = c ? (q0 + k) : i0;
            v0 = c ? v : v0;
        }
        // ordered 3-way merge via shuffles (leader lane gets chunks j=1,2 from lane+1,+2)
        {
            float av0 = __shfl_down(v0, 1), av1 = __shfl_down(v1, 1);
            int   ai0 = __shfl_down(i0, 1);
            float bv0 = __shfl_down(v0, 2), bv1 = __shfl_down(v1, 2);
            int   bi0 = __shfl_down(i0, 2);
            if (av0 > v0) { v1 = fmaxf(v0, av1); v0 = av0; i0 = ai0; }
            else          { v1 = fmaxf(av0, v1); }
            if (bv0 > v0) { v1 = fmaxf(v0, bv1); v0 = bv0; i0 = bi0; }
            else          { v1 = fmaxf(bv0, v1); }
        }
        float mybid = price[i0] + (v0 - v1) + eps;   // exact ref op order
        if (is_leader) { bidv[myt] = mybid; bo[myt] = i0; }
        __syncthreads();

        // resolution: only unassigned bidders (bits of U); strict '>' + lower-t tie-break
        const bool act = is_leader && (((U >> lane) & 1ull) != 0ull);
        if (act) {
            bool lose = false;
            unsigned long long u = U;
            while (u) {
                int pos = __builtin_ctzll(u); u &= (u - 1);
                int t2 = pos / 3;
                if (t2 != myt) {
                    float bv = bidv[t2]; int ob = bo[t2];   // broadcast LDS reads
                    lose = lose || (ob == i0 && (bv > mybid || (bv == mybid && t2 < myt)));
                }
            }
            if (!lose) {                       // winner: distinct q among winners
                int q = i0;
                int old = owner[q];
                owner[q] = myt;
                price[q] = mybid;
                myobj = q;
                if (old >= 0) evict[old] = 1;  // evictees disjoint from winners
            }
        }
        __syncthreads();
        if (is_leader && evict[myt]) { myobj = -1; evict[myt] = 0; }
    }
    __syncthreads();
    if (is_leader) objl[myt] = myobj;
    __syncthreads();

    // ---- stable argsort of obj_of (rank computation) ----
    if (lane < TN) {
        int v = objl[lane];
        int r = 0;
        for (int u = 0; u < TN; ++u) {
            int w = objl[u];
            r += (w < v) || (w == v && u < lane);
        }
        out_pred[(size_t)bf * TN + r] = (float)v;
        out_tgt[(size_t)bf * TN + r]  = (float)lane;
    }
}

extern "C" void kernel_launch(void* const* d_in, const int* in_sizes, int n_in,
                              void* d_out, int out_size, void* d_ws, size_t ws_size,
                              hipStream_t stream) {
    const float* logits  = (const float*)d_in[0];
    const float* pboxes  = (const float*)d_in[1];
    const int*   tlabels = (const int*)d_in[2];
    const float* tboxes  = (const float*)d_in[3];

    float* out = (float*)d_out;
    float* out_cost = out;                                   // 64*36*100*20
    float* out_pred = out + (size_t)NB * NF * QN * TN;       // 64*36*20
    float* out_tgt  = out_pred + (size_t)NB * NF * TN;       // 64*36*20

    hipLaunchKernelGGL(matcher_kernel, dim3(NB * NF), dim3(64), 0, stream,
                       logits, pboxes, tlabels, tboxes, out_cost, out_pred, out_tgt);
}